// Round 3
// baseline (198.445 us; speedup 1.0000x reference)
//
#include <hip/hip_runtime.h>

typedef unsigned short u16;
typedef short bf16x8 __attribute__((ext_vector_type(8)));
typedef float f32x4 __attribute__((ext_vector_type(4)));
typedef u16 u16x4 __attribute__((ext_vector_type(4)));

__device__ __forceinline__ float b2f(u16 h) {
  unsigned u = ((unsigned)h) << 16;
  return __builtin_bit_cast(float, u);
}
// native RTNE f32->bf16; compiler pairs these into v_cvt_pk_bf16_f32
__device__ __forceinline__ u16 f2b(float f) {
  return __builtin_bit_cast(u16, (__bf16)f);
}
__device__ __forceinline__ void gld_lds16(const void* g, void* l) {
  __builtin_amdgcn_global_load_lds(
      (__attribute__((address_space(1))) void*)(g),
      (__attribute__((address_space(3))) void*)(l), 16, 0, 0);
}

// ---------------------------------------------------------------------------
// prep (merged): blocks [0,160): fp32 [o][c] weights -> bf16 STAGED layout
//   [layer][s8(32)][m(256)][8]  (a wave's A-frag reads are 256B-contiguous)
//   layers: 0,1 = post_w[0..1]; 2,3,4 = pre_w[0..2]
// blocks [160,416): x [2][256][1024] fp32 -> xt [2048][256] bf16 (transpose)
// ---------------------------------------------------------------------------
__global__ void dense_edge_prep(const float* __restrict__ x,
                                const float* __restrict__ pre_w,
                                const float* __restrict__ post_w,
                                u16* __restrict__ wb, u16* __restrict__ xt) {
  const int blk = blockIdx.x;
  const int t = threadIdx.x;
  if (blk < 160) {
    const int id = blk * 256 + t;      // 40960 slots of 8 elems
    const int layer = id >> 13;        // 0..4
    const int sid = id & 8191;
    const int m = sid >> 5;
    const int s8 = sid & 31;
    const float* src = (layer < 2) ? (post_w + layer * 65536)
                                   : (pre_w + (layer - 2) * 65536);
    u16* dst = wb + layer * 65536;
    f32x4 a = *(const f32x4*)(src + m * 256 + s8 * 8);
    f32x4 c = *(const f32x4*)(src + m * 256 + s8 * 8 + 4);
    bf16x8 o;
#pragma unroll
    for (int j = 0; j < 4; j++) o[j] = (short)f2b(a[j]);
#pragma unroll
    for (int j = 0; j < 4; j++) o[4 + j] = (short)f2b(c[j]);
    *(bf16x8*)(dst + (s8 * 256 + m) * 8) = o;
  } else {
    __shared__ float tile[32 * 65];
    const int xb = blk - 160;          // 2 b x 8 ctile x 16 hwtile = 256
    const int b = xb >> 7;
    const int ct = (xb >> 4) & 7;
    const int ht = xb & 15;
    const int c0 = ct * 32, hw0 = ht * 64;
#pragma unroll
    for (int rep = 0; rep < 8; rep++) {
      const int idx = rep * 256 + t;
      const int cl = idx >> 6, hl = idx & 63;
      tile[cl * 65 + hl] = x[(b * 256 + c0 + cl) * 1024 + hw0 + hl];
    }
    __syncthreads();
    const int hl = t >> 2, c8 = t & 3;
    bf16x8 o;
#pragma unroll
    for (int i = 0; i < 8; i++) o[i] = (short)f2b(tile[(c8 * 8 + i) * 65 + hl]);
    *(bf16x8*)(xt + (b * 1024 + hw0 + hl) * 256 + c0 + c8 * 8) = o;
  }
}

// ---------------------------------------------------------------------------
// pre_gemm: 3-layer 1x1-conv chain on 2048 nodes, bf16 MFMA.
// ---------------------------------------------------------------------------
__global__ __launch_bounds__(256, 2) void dense_edge_pre(
    const u16* __restrict__ xt, const u16* __restrict__ wpre,
    const float* __restrict__ preb, u16* __restrict__ flat) {
  __shared__ u16 feat[2][4096];  // [32 s8][16 n][8] each
  const int t = threadIdx.x;
  const int wv = t >> 6, ln = t & 63;
  const int nb = blockIdx.x * 16;
  const int q4 = ln >> 4, r15 = ln & 15;

#pragma unroll
  for (int i = 0; i < 2; i++) {
    const int slot = wv * 128 + i * 64 + ln;
    const int s8 = slot >> 4, nl = slot & 15;
    gld_lds16(xt + (nb + nl) * 256 + s8 * 8, &feat[0][slot * 8]);
  }
  __syncthreads();

#pragma unroll
  for (int l = 0; l < 3; l++) {
    const u16* wl = wpre + l * 65536;
    f32x4 acc[4];
    f32x4 zero = {0.f, 0.f, 0.f, 0.f};
#pragma unroll
    for (int mt = 0; mt < 4; mt++) acc[mt] = zero;
#pragma unroll
    for (int s = 0; s < 8; s++) {
      bf16x8 bv = *(const bf16x8*)(&feat[l & 1][((s * 4 + q4) * 16 + r15) * 8]);
#pragma unroll
      for (int mt = 0; mt < 4; mt++) {
        bf16x8 av = *(const bf16x8*)(wl + ((s * 4 + q4) * 256 + wv * 64 + mt * 16 + r15) * 8);
        acc[mt] = __builtin_amdgcn_mfma_f32_16x16x32_bf16(av, bv, acc[mt], 0, 0, 0);
      }
    }
    if (l < 2) {
#pragma unroll
      for (int mt = 0; mt < 4; mt++) {
        const int o = wv * 64 + mt * 16 + q4 * 4;
        f32x4 bb = *(const f32x4*)(preb + l * 256 + o);
        u16x4 pk;
#pragma unroll
        for (int r = 0; r < 4; r++) {
          float v = fmaxf(acc[mt][r] + bb[r], 0.f);
          pk[r] = f2b(v);
        }
        *(u16x4*)(&feat[(l + 1) & 1][((o >> 3) * 16 + r15) * 8 + (o & 7)]) = pk;
      }
      __syncthreads();
    } else {
#pragma unroll
      for (int mt = 0; mt < 4; mt++) {
        const int o = wv * 64 + mt * 16 + q4 * 4;
        f32x4 bb = *(const f32x4*)(preb + 512 + o);
        u16x4 pk;
#pragma unroll
        for (int r = 0; r < 4; r++) pk[r] = f2b(acc[mt][r] + bb[r]);  // no relu
        *(u16x4*)(flat + (nb + r15) * 256 + o) = pk;
      }
    }
  }
}

// ---------------------------------------------------------------------------
// main: fused GEMM1+GEMM2+W3 with wave specialization.
// NEW vs prev round: 512 blocks x 4 tiles (was 256 x 8) -> 2 blocks/CU
// co-resident (LDS 78 KB x 2 = 156 KB <= 160 KB). Inter-block overlap hides
// barrier drains that a single resident block fully exposes.
// ---------------------------------------------------------------------------
#define NT 4  // tiles per block
__global__ __launch_bounds__(512, 4) void dense_edge_main(
    const u16* __restrict__ flat, const int* __restrict__ pidx,
    const int* __restrict__ cidx, const u16* __restrict__ w1s,
    const u16* __restrict__ w2s, const float* __restrict__ b1,
    const float* __restrict__ b2, const float* __restrict__ w3,
    const float* __restrict__ b3, float* __restrict__ out) {
  __shared__ u16 xxbuf[16384];      // 32 KB [s8(32)][n(64)][8]
  __shared__ u16 t1buf[16384];      // 32 KB, same layout
  __shared__ u16 pstage[2048];      // 4 KB p-rows [cw][chunk8][row8][8]
  __shared__ u16 qstage[2][2048];   // 8 KB q-rows, double-buffered
  __shared__ float pbuf[4][2][64];  // 2 KB consumer partials

  const int t = threadIdx.x;
  const int wv = t >> 6;
  const int ln = t & 63;
  const int q4 = ln >> 4, r15 = ln & 15;
  const bool prod = wv < 4;
  const int cw = wv & 3;            // lane-group / m-quarter within role
  const int blk = blockIdx.x;
  const int tile0 = blk * NT;
  const int b = tile0 >> 10;
  const int pt = (tile0 >> 5) & 31;
  const int qt0 = tile0 & 31;
  const int p0 = pt * 8;

  // role weights into registers (coalesced 256B segments from staged layout)
  const u16* wsrc = prod ? w1s : w2s;
  bf16x8 af_w[4][8];
#pragma unroll
  for (int s = 0; s < 8; s++)
#pragma unroll
    for (int mt = 0; mt < 4; mt++)
      af_w[mt][s] = *(const bf16x8*)(wsrc + ((s * 4 + q4) * 256 + cw * 64 + mt * 16 + r15) * 8);

  // stage p-rows (constant across the block's NT tiles) and q-rows for tile 0
  if (prod) {
    const int pn = pidx[b * 256 + p0 + (ln & 7)];
    gld_lds16(flat + pn * 256 + cw * 64 + (ln >> 3) * 8, &pstage[cw * 512 + ln * 8]);
    const int qn0 = cidx[b * 256 + qt0 * 8 + (ln & 7)];
    gld_lds16(flat + qn0 * 256 + cw * 64 + (ln >> 3) * 8, &qstage[0][cw * 512 + ln * 8]);
  }
  __syncthreads();

#pragma unroll 1
  for (int j = 0; j <= NT; j++) {
    // ---------------- P1 ----------------
    if (prod) {
      if (j < NT) {
        // prefetch index for tile j+1 early (latency overlaps XX compute)
        int qn_next = 0;
        if (j < NT - 1) qn_next = cidx[b * 256 + (qt0 + j + 1) * 8 + (ln & 7)];
        const u16* pq = &pstage[cw * 512 + (ln >> 3) * 8];
        const u16* qq = &qstage[j & 1][cw * 512 + (ln & 7) * 8];
#pragma unroll
        for (int i = 0; i < 8; i++) {
          bf16x8 av = *(const bf16x8*)(pq + i * 64);
          bf16x8 bv = *(const bf16x8*)(qq + i * 64);
          bf16x8 ov;
#pragma unroll
          for (int jj = 0; jj < 8; jj++) {
            float d = b2f((u16)av[jj]) - b2f((u16)bv[jj]);
            ov[jj] = (short)f2b(d * d);
          }
          *(bf16x8*)(xxbuf + ((cw * 8 + i) * 64 + ln) * 8) = ov;
        }
        // issue q-gather for tile j+1; lands under the P1 barrier drain
        if (j < NT - 1)
          gld_lds16(flat + qn_next * 256 + cw * 64 + (ln >> 3) * 8,
                    &qstage[(j + 1) & 1][cw * 512 + ln * 8]);
      }
    } else if (j > 0) {
      // GEMM2 on tile j-1 from t1buf
      f32x4 acc[4][4];
      {
        f32x4 zero = {0.f, 0.f, 0.f, 0.f};
#pragma unroll
        for (int mt = 0; mt < 4; mt++)
#pragma unroll
          for (int nt = 0; nt < 4; nt++) acc[mt][nt] = zero;
      }
#pragma unroll
      for (int s = 0; s < 8; s++) {
        bf16x8 bfr[4];
#pragma unroll
        for (int nt = 0; nt < 4; nt++)
          bfr[nt] = *(const bf16x8*)(t1buf + ((s * 4 + q4) * 64 + nt * 16 + r15) * 8);
#pragma unroll
        for (int mt = 0; mt < 4; mt++)
#pragma unroll
          for (int nt = 0; nt < 4; nt++)
            acc[mt][nt] = __builtin_amdgcn_mfma_f32_16x16x32_bf16(af_w[mt][s], bfr[nt], acc[mt][nt], 0, 0, 0);
      }
      // W3 epilogue partials: relu(acc+b2) dotted with w3 rows
      float part[2][4] = {{0.f, 0.f, 0.f, 0.f}, {0.f, 0.f, 0.f, 0.f}};
#pragma unroll
      for (int mt = 0; mt < 4; mt++) {
        const int o = cw * 64 + mt * 16 + q4 * 4;
        f32x4 bb = *(const f32x4*)(b2 + o);
        f32x4 w3a = *(const f32x4*)(w3 + o);
        f32x4 w3b = *(const f32x4*)(w3 + 256 + o);
#pragma unroll
        for (int nt = 0; nt < 4; nt++) {
#pragma unroll
          for (int r = 0; r < 4; r++) {
            float v = fmaxf(acc[mt][nt][r] + bb[r], 0.f);
            part[0][nt] += v * w3a[r];
            part[1][nt] += v * w3b[r];
          }
        }
      }
#pragma unroll
      for (int o3 = 0; o3 < 2; o3++)
#pragma unroll
        for (int nt = 0; nt < 4; nt++) {
          part[o3][nt] += __shfl_xor(part[o3][nt], 16, 64);
          part[o3][nt] += __shfl_xor(part[o3][nt], 32, 64);
        }
      if (q4 == 0) {
#pragma unroll
        for (int o3 = 0; o3 < 2; o3++)
#pragma unroll
          for (int nt = 0; nt < 4; nt++)
            pbuf[cw][o3][nt * 16 + r15] = part[o3][nt];
      }
    }
    __syncthreads();

    // ---------------- P2 ----------------
    if (prod) {
      if (j < NT) {
        f32x4 acc[4][4];
        {
          f32x4 zero = {0.f, 0.f, 0.f, 0.f};
#pragma unroll
          for (int mt = 0; mt < 4; mt++)
#pragma unroll
            for (int nt = 0; nt < 4; nt++) acc[mt][nt] = zero;
        }
#pragma unroll
        for (int s = 0; s < 8; s++) {
          bf16x8 bfr[4];
#pragma unroll
          for (int nt = 0; nt < 4; nt++)
            bfr[nt] = *(const bf16x8*)(xxbuf + ((s * 4 + q4) * 64 + nt * 16 + r15) * 8);
#pragma unroll
          for (int mt = 0; mt < 4; mt++)
#pragma unroll
            for (int nt = 0; nt < 4; nt++)
              acc[mt][nt] = __builtin_amdgcn_mfma_f32_16x16x32_bf16(af_w[mt][s], bfr[nt], acc[mt][nt], 0, 0, 0);
        }
        // relu + b1 -> t1buf (staged layout)
#pragma unroll
        for (int mt = 0; mt < 4; mt++) {
          const int o = cw * 64 + mt * 16 + q4 * 4;
          f32x4 bb = *(const f32x4*)(b1 + o);
#pragma unroll
          for (int nt = 0; nt < 4; nt++) {
            const int nn = nt * 16 + r15;
            u16x4 pk;
#pragma unroll
            for (int r = 0; r < 4; r++) {
              float v = fmaxf(acc[mt][nt][r] + bb[r], 0.f);
              pk[r] = f2b(v);
            }
            *(u16x4*)(t1buf + ((o >> 3) * 64 + nn) * 8 + (o & 7)) = pk;
          }
        }
      }
    } else if (j > 0) {
      const int idx = t & 255;
      if (idx < 128) {
        const int o3 = idx >> 6;
        const int n = idx & 63;
        float v = pbuf[0][o3][n] + pbuf[1][o3][n] + pbuf[2][o3][n] + pbuf[3][o3][n] + b3[o3];
        out[((b * 2 + o3) * 256 + p0 + (n >> 3)) * 256 + (qt0 + j - 1) * 8 + (n & 7)] = v;
      }
    }
    __syncthreads();
  }
}

// ---------------------------------------------------------------------------
extern "C" void kernel_launch(void* const* d_in, const int* in_sizes, int n_in,
                              void* d_out, int out_size, void* d_ws, size_t ws_size,
                              hipStream_t stream) {
  (void)in_sizes; (void)n_in; (void)out_size; (void)ws_size;
  const float* x          = (const float*)d_in[0];
  const int*   pidx       = (const int*)d_in[1];
  const int*   cidx       = (const int*)d_in[2];
  const float* pre_w      = (const float*)d_in[3];
  const float* pre_b      = (const float*)d_in[4];
  const float* post_w     = (const float*)d_in[5];
  const float* post_b     = (const float*)d_in[6];
  const float* post_out_w = (const float*)d_in[7];
  const float* post_out_b = (const float*)d_in[8];
  float* out = (float*)d_out;

  u16* ws   = (u16*)d_ws;
  u16* wb   = ws;              // staged bf16 weights: w1,w2,pre0,pre1,pre2
  u16* w1s  = wb;
  u16* w2s  = wb + 65536;
  u16* wpre = wb + 131072;
  u16* xt   = ws + 327680;     // x_t bf16 [2048][256]
  u16* flat = ws + 851968;     // node features bf16 [2048][256]

  dense_edge_prep<<<416, 256, 0, stream>>>(x, pre_w, post_w, wb, xt);
  dense_edge_pre<<<128, 256, 0, stream>>>(xt, wpre, pre_b, flat);
  dense_edge_main<<<512, 512, 0, stream>>>(flat, pidx, cidx, w1s, w2s,
                                           post_b, post_b + 256,
                                           post_out_w, post_out_b, out);
}

// Round 4
// 126.323 us; speedup vs baseline: 1.5709x; 1.5709x over previous
//
#include <hip/hip_runtime.h>

typedef unsigned short u16;
typedef short bf16x8 __attribute__((ext_vector_type(8)));
typedef float f32x4 __attribute__((ext_vector_type(4)));
typedef u16 u16x4 __attribute__((ext_vector_type(4)));

__device__ __forceinline__ float b2f(u16 h) {
  unsigned u = ((unsigned)h) << 16;
  return __builtin_bit_cast(float, u);
}
// native RTNE f32->bf16; compiler pairs these into v_cvt_pk_bf16_f32
__device__ __forceinline__ u16 f2b(float f) {
  return __builtin_bit_cast(u16, (__bf16)f);
}
__device__ __forceinline__ void gld_lds16(const void* g, void* l) {
  __builtin_amdgcn_global_load_lds(
      (__attribute__((address_space(1))) void*)(g),
      (__attribute__((address_space(3))) void*)(l), 16, 0, 0);
}

// ---------------------------------------------------------------------------
// prep (merged): blocks [0,160): fp32 [o][c] weights -> bf16 STAGED layout
//   [layer][s8(32)][m(256)][8]  (a wave's A-frag reads are 256B-contiguous)
//   layers: 0,1 = post_w[0..1]; 2,3,4 = pre_w[0..2]
// blocks [160,416): x [2][256][1024] fp32 -> xt [2048][256] bf16 (transpose)
// ---------------------------------------------------------------------------
__global__ void dense_edge_prep(const float* __restrict__ x,
                                const float* __restrict__ pre_w,
                                const float* __restrict__ post_w,
                                u16* __restrict__ wb, u16* __restrict__ xt) {
  const int blk = blockIdx.x;
  const int t = threadIdx.x;
  if (blk < 160) {
    const int id = blk * 256 + t;      // 40960 slots of 8 elems
    const int layer = id >> 13;        // 0..4
    const int sid = id & 8191;
    const int m = sid >> 5;
    const int s8 = sid & 31;
    const float* src = (layer < 2) ? (post_w + layer * 65536)
                                   : (pre_w + (layer - 2) * 65536);
    u16* dst = wb + layer * 65536;
    f32x4 a = *(const f32x4*)(src + m * 256 + s8 * 8);
    f32x4 c = *(const f32x4*)(src + m * 256 + s8 * 8 + 4);
    bf16x8 o;
#pragma unroll
    for (int j = 0; j < 4; j++) o[j] = (short)f2b(a[j]);
#pragma unroll
    for (int j = 0; j < 4; j++) o[4 + j] = (short)f2b(c[j]);
    *(bf16x8*)(dst + (s8 * 256 + m) * 8) = o;
  } else {
    __shared__ float tile[32 * 65];
    const int xb = blk - 160;          // 2 b x 8 ctile x 16 hwtile = 256
    const int b = xb >> 7;
    const int ct = (xb >> 4) & 7;
    const int ht = xb & 15;
    const int c0 = ct * 32, hw0 = ht * 64;
#pragma unroll
    for (int rep = 0; rep < 8; rep++) {
      const int idx = rep * 256 + t;
      const int cl = idx >> 6, hl = idx & 63;
      tile[cl * 65 + hl] = x[(b * 256 + c0 + cl) * 1024 + hw0 + hl];
    }
    __syncthreads();
    const int hl = t >> 2, c8 = t & 3;
    bf16x8 o;
#pragma unroll
    for (int i = 0; i < 8; i++) o[i] = (short)f2b(tile[(c8 * 8 + i) * 65 + hl]);
    *(bf16x8*)(xt + (b * 1024 + hw0 + hl) * 256 + c0 + c8 * 8) = o;
  }
}

// ---------------------------------------------------------------------------
// pre_gemm: 3-layer 1x1-conv chain on 2048 nodes, bf16 MFMA.
// ---------------------------------------------------------------------------
__global__ __launch_bounds__(256, 2) void dense_edge_pre(
    const u16* __restrict__ xt, const u16* __restrict__ wpre,
    const float* __restrict__ preb, u16* __restrict__ flat) {
  __shared__ u16 feat[2][4096];  // [32 s8][16 n][8] each
  const int t = threadIdx.x;
  const int wv = t >> 6, ln = t & 63;
  const int nb = blockIdx.x * 16;
  const int q4 = ln >> 4, r15 = ln & 15;

#pragma unroll
  for (int i = 0; i < 2; i++) {
    const int slot = wv * 128 + i * 64 + ln;
    const int s8 = slot >> 4, nl = slot & 15;
    gld_lds16(xt + (nb + nl) * 256 + s8 * 8, &feat[0][slot * 8]);
  }
  __syncthreads();

#pragma unroll
  for (int l = 0; l < 3; l++) {
    const u16* wl = wpre + l * 65536;
    f32x4 acc[4];
    f32x4 zero = {0.f, 0.f, 0.f, 0.f};
#pragma unroll
    for (int mt = 0; mt < 4; mt++) acc[mt] = zero;
#pragma unroll
    for (int s = 0; s < 8; s++) {
      bf16x8 bv = *(const bf16x8*)(&feat[l & 1][((s * 4 + q4) * 16 + r15) * 8]);
#pragma unroll
      for (int mt = 0; mt < 4; mt++) {
        bf16x8 av = *(const bf16x8*)(wl + ((s * 4 + q4) * 256 + wv * 64 + mt * 16 + r15) * 8);
        acc[mt] = __builtin_amdgcn_mfma_f32_16x16x32_bf16(av, bv, acc[mt], 0, 0, 0);
      }
    }
    if (l < 2) {
#pragma unroll
      for (int mt = 0; mt < 4; mt++) {
        const int o = wv * 64 + mt * 16 + q4 * 4;
        f32x4 bb = *(const f32x4*)(preb + l * 256 + o);
        u16x4 pk;
#pragma unroll
        for (int r = 0; r < 4; r++) {
          float v = fmaxf(acc[mt][r] + bb[r], 0.f);
          pk[r] = f2b(v);
        }
        *(u16x4*)(&feat[(l + 1) & 1][((o >> 3) * 16 + r15) * 8 + (o & 7)]) = pk;
      }
      __syncthreads();
    } else {
#pragma unroll
      for (int mt = 0; mt < 4; mt++) {
        const int o = wv * 64 + mt * 16 + q4 * 4;
        f32x4 bb = *(const f32x4*)(preb + 512 + o);
        u16x4 pk;
#pragma unroll
        for (int r = 0; r < 4; r++) pk[r] = f2b(acc[mt][r] + bb[r]);  // no relu
        *(u16x4*)(flat + (nb + r15) * 256 + o) = pk;
      }
    }
  }
}

// ---------------------------------------------------------------------------
// main: fused GEMM1+GEMM2+W3, wave-specialized, 16 waves/block.
// NEW vs round 2: 1024 threads (8 producer + 8 consumer waves), each wave
// holds HALF the previous weight slice (af_w[2][8] = 64 VGPR, acc[2][4]).
// Total regs ~125/wave -> fits __launch_bounds__(1024,4) WITHOUT spill
// (round-3 lesson: 4-waves/EU with af_w[4][8] spills catastrophically).
// 4 waves/SIMD (2 prod + 2 cons) interleave issue -> matrix pipe stays fed
// through ds_read / barrier bubbles that 2 waves/SIMD fully exposed.
// Stage layout [cchunk(32)][row(8)][8]: row stride 16B -> 8 rows spread
// across all banks (conflict-free XX reads), and lane-linear for gld_lds.
// ---------------------------------------------------------------------------
#define NT 8  // tiles per block
__global__ __launch_bounds__(1024, 4) void dense_edge_main(
    const u16* __restrict__ flat, const int* __restrict__ pidx,
    const int* __restrict__ cidx, const u16* __restrict__ w1s,
    const u16* __restrict__ w2s, const float* __restrict__ b1,
    const float* __restrict__ b2, const float* __restrict__ w3,
    const float* __restrict__ b3, float* __restrict__ out) {
  __shared__ u16 xxbuf[16384];      // 32 KB [s8(32)][n(64)][8]
  __shared__ u16 t1buf[16384];      // 32 KB, same layout
  __shared__ u16 pstage[2048];      // 4 KB p-rows [cchunk(32)][row(8)][8]
  __shared__ u16 qstage[2][2048];   // 8 KB q-rows, double-buffered
  __shared__ float pbuf[8][2][64];  // 4 KB consumer partials

  const int t = threadIdx.x;
  const int wv = t >> 6;
  const int ln = t & 63;
  const int q4 = ln >> 4, r15 = ln & 15;
  const bool prod = wv < 8;
  const int w8 = wv & 7;            // wave index within role
  const int blk = blockIdx.x;
  const int tile0 = blk * NT;
  const int b = tile0 >> 10;
  const int pt = (tile0 >> 5) & 31;
  const int qt0 = tile0 & 31;
  const int p0 = pt * 8;

  // role weights: 8 waves/role, 32 m-rows each (2 mt); staged layout gives
  // 256B-contiguous reads per (s,q4) group.
  const u16* wsrc = prod ? w1s : w2s;
  bf16x8 af_w[2][8];
#pragma unroll
  for (int s = 0; s < 8; s++)
#pragma unroll
    for (int mt = 0; mt < 2; mt++)
      af_w[mt][s] = *(const bf16x8*)(wsrc + ((s * 4 + q4) * 256 + w8 * 32 + mt * 16 + r15) * 8);

  // initial staging: producer waves 0-3 -> pstage, 4-7 -> qstage[0].
  // slot = cchunk*8 + row; dest lane-linear; global src per-lane.
  if (prod) {
    const int slot = (w8 & 3) * 64 + ln;
    const int row = slot & 7, cc = slot >> 3;
    if (w8 < 4) {
      const int pn = pidx[b * 256 + p0 + row];
      gld_lds16(flat + pn * 256 + cc * 8, &pstage[slot * 8]);
    } else {
      const int qn = cidx[b * 256 + qt0 * 8 + row];
      gld_lds16(flat + qn * 256 + cc * 8, &qstage[0][slot * 8]);
    }
  }
  __syncthreads();

#pragma unroll 1
  for (int j = 0; j <= NT; j++) {
    // ---------------- P1 ----------------
    if (prod) {
      if (j < NT) {
        // next-tile q index load early (hides L2 latency under XX build)
        const bool restage = (j < NT - 1) && (w8 >= 4);
        int qn_next = 0, rslot = 0;
        if (restage) {
          rslot = (w8 - 4) * 64 + ln;
          qn_next = cidx[b * 256 + (qt0 + j + 1) * 8 + (rslot & 7)];
        }
        const u16* qs = qstage[j & 1];
        const int prow = ln >> 3, qrow = ln & 7;
#pragma unroll
        for (int i = 0; i < 4; i++) {
          const int cc = w8 * 4 + i;
          bf16x8 av = *(const bf16x8*)(&pstage[(cc * 8 + prow) * 8]);
          bf16x8 bv = *(const bf16x8*)(&qs[(cc * 8 + qrow) * 8]);
          bf16x8 ov;
#pragma unroll
          for (int jj = 0; jj < 8; jj++) {
            float d = b2f((u16)av[jj]) - b2f((u16)bv[jj]);
            ov[jj] = (short)f2b(d * d);
          }
          *(bf16x8*)(xxbuf + ((cc)*64 + ln) * 8) = ov;
        }
        // issue q-gather for tile j+1; completes at this phase's barrier
        if (restage)
          gld_lds16(flat + qn_next * 256 + (rslot >> 3) * 8,
                    &qstage[(j + 1) & 1][rslot * 8]);
      }
    } else if (j > 0) {
      // GEMM2 on tile j-1 from t1buf
      f32x4 acc[2][4];
      {
        f32x4 zero = {0.f, 0.f, 0.f, 0.f};
#pragma unroll
        for (int mt = 0; mt < 2; mt++)
#pragma unroll
          for (int nt = 0; nt < 4; nt++) acc[mt][nt] = zero;
      }
#pragma unroll
      for (int s = 0; s < 8; s++) {
        bf16x8 bfr[4];
#pragma unroll
        for (int nt = 0; nt < 4; nt++)
          bfr[nt] = *(const bf16x8*)(t1buf + ((s * 4 + q4) * 64 + nt * 16 + r15) * 8);
#pragma unroll
        for (int mt = 0; mt < 2; mt++)
#pragma unroll
          for (int nt = 0; nt < 4; nt++)
            acc[mt][nt] = __builtin_amdgcn_mfma_f32_16x16x32_bf16(af_w[mt][s], bfr[nt], acc[mt][nt], 0, 0, 0);
      }
      // W3 epilogue partials: relu(acc+b2) dotted with w3 rows
      float part[2][4] = {{0.f, 0.f, 0.f, 0.f}, {0.f, 0.f, 0.f, 0.f}};
#pragma unroll
      for (int mt = 0; mt < 2; mt++) {
        const int o = w8 * 32 + mt * 16 + q4 * 4;
        f32x4 bb = *(const f32x4*)(b2 + o);
        f32x4 w3a = *(const f32x4*)(w3 + o);
        f32x4 w3b = *(const f32x4*)(w3 + 256 + o);
#pragma unroll
        for (int nt = 0; nt < 4; nt++) {
#pragma unroll
          for (int r = 0; r < 4; r++) {
            float v = fmaxf(acc[mt][nt][r] + bb[r], 0.f);
            part[0][nt] += v * w3a[r];
            part[1][nt] += v * w3b[r];
          }
        }
      }
#pragma unroll
      for (int o3 = 0; o3 < 2; o3++)
#pragma unroll
        for (int nt = 0; nt < 4; nt++) {
          part[o3][nt] += __shfl_xor(part[o3][nt], 16, 64);
          part[o3][nt] += __shfl_xor(part[o3][nt], 32, 64);
        }
      if (q4 == 0) {
#pragma unroll
        for (int o3 = 0; o3 < 2; o3++)
#pragma unroll
          for (int nt = 0; nt < 4; nt++)
            pbuf[w8][o3][nt * 16 + r15] = part[o3][nt];
      }
    }
    __syncthreads();

    // ---------------- P2 ----------------
    if (prod) {
      if (j < NT) {
        f32x4 acc[2][4];
        {
          f32x4 zero = {0.f, 0.f, 0.f, 0.f};
#pragma unroll
          for (int mt = 0; mt < 2; mt++)
#pragma unroll
            for (int nt = 0; nt < 4; nt++) acc[mt][nt] = zero;
        }
#pragma unroll
        for (int s = 0; s < 8; s++) {
          bf16x8 bfr[4];
#pragma unroll
          for (int nt = 0; nt < 4; nt++)
            bfr[nt] = *(const bf16x8*)(xxbuf + ((s * 4 + q4) * 64 + nt * 16 + r15) * 8);
#pragma unroll
          for (int mt = 0; mt < 2; mt++)
#pragma unroll
            for (int nt = 0; nt < 4; nt++)
              acc[mt][nt] = __builtin_amdgcn_mfma_f32_16x16x32_bf16(af_w[mt][s], bfr[nt], acc[mt][nt], 0, 0, 0);
        }
        // relu + b1 -> t1buf (staged layout)
#pragma unroll
        for (int mt = 0; mt < 2; mt++) {
          const int o = w8 * 32 + mt * 16 + q4 * 4;
          f32x4 bb = *(const f32x4*)(b1 + o);
#pragma unroll
          for (int nt = 0; nt < 4; nt++) {
            const int nn = nt * 16 + r15;
            u16x4 pk;
#pragma unroll
            for (int r = 0; r < 4; r++) {
              float v = fmaxf(acc[mt][nt][r] + bb[r], 0.f);
              pk[r] = f2b(v);
            }
            *(u16x4*)(t1buf + ((o >> 3) * 64 + nn) * 8 + (o & 7)) = pk;
          }
        }
      }
    } else if (j > 0) {
      if (wv < 10) {  // waves 8,9: 128 outputs of tile j-1
        const int idx = (wv - 8) * 64 + ln;
        const int o3 = idx >> 6;
        const int n = idx & 63;
        float v = b3[o3];
#pragma unroll
        for (int k = 0; k < 8; k++) v += pbuf[k][o3][n];
        out[((b * 2 + o3) * 256 + p0 + (n >> 3)) * 256 + (qt0 + j - 1) * 8 + (n & 7)] = v;
      }
    }
    __syncthreads();
  }
}

// ---------------------------------------------------------------------------
extern "C" void kernel_launch(void* const* d_in, const int* in_sizes, int n_in,
                              void* d_out, int out_size, void* d_ws, size_t ws_size,
                              hipStream_t stream) {
  (void)in_sizes; (void)n_in; (void)out_size; (void)ws_size;
  const float* x          = (const float*)d_in[0];
  const int*   pidx       = (const int*)d_in[1];
  const int*   cidx       = (const int*)d_in[2];
  const float* pre_w      = (const float*)d_in[3];
  const float* pre_b      = (const float*)d_in[4];
  const float* post_w     = (const float*)d_in[5];
  const float* post_b     = (const float*)d_in[6];
  const float* post_out_w = (const float*)d_in[7];
  const float* post_out_b = (const float*)d_in[8];
  float* out = (float*)d_out;

  u16* ws   = (u16*)d_ws;
  u16* wb   = ws;              // staged bf16 weights: w1,w2,pre0,pre1,pre2
  u16* w1s  = wb;
  u16* w2s  = wb + 65536;
  u16* wpre = wb + 131072;
  u16* xt   = ws + 327680;     // x_t bf16 [2048][256]
  u16* flat = ws + 851968;     // node features bf16 [2048][256]

  dense_edge_prep<<<416, 256, 0, stream>>>(x, pre_w, post_w, wb, xt);
  dense_edge_pre<<<128, 256, 0, stream>>>(xt, wpre, pre_b, flat);
  dense_edge_main<<<256, 1024, 0, stream>>>(flat, pidx, cidx, w1s, w2s,
                                            post_b, post_b + 256,
                                            post_out_w, post_out_b, out);
}

// Round 5
// 119.519 us; speedup vs baseline: 1.6604x; 1.0569x over previous
//
#include <hip/hip_runtime.h>

typedef unsigned short u16;
typedef short bf16x8 __attribute__((ext_vector_type(8)));
typedef float f32x4 __attribute__((ext_vector_type(4)));
typedef u16 u16x4 __attribute__((ext_vector_type(4)));

__device__ __forceinline__ float b2f(u16 h) {
  unsigned u = ((unsigned)h) << 16;
  return __builtin_bit_cast(float, u);
}
// native RTNE f32->bf16; compiler pairs these into v_cvt_pk_bf16_f32
__device__ __forceinline__ u16 f2b(float f) {
  return __builtin_bit_cast(u16, (__bf16)f);
}
__device__ __forceinline__ void gld_lds16(const void* g, void* l) {
  __builtin_amdgcn_global_load_lds(
      (__attribute__((address_space(1))) void*)(g),
      (__attribute__((address_space(3))) void*)(l), 16, 0, 0);
}

// ---------------------------------------------------------------------------
// prep (merged): blocks [0,160): fp32 [o][c] weights -> bf16 STAGED layout
//   [layer][s8(32)][m(256)][8]  (a wave's A-frag reads are 256B-contiguous)
//   layers: 0,1 = post_w[0..1]; 2,3,4 = pre_w[0..2]
// blocks [160,416): x [2][256][1024] fp32 -> xt [2048][256] bf16 (transpose)
// ---------------------------------------------------------------------------
__global__ void dense_edge_prep(const float* __restrict__ x,
                                const float* __restrict__ pre_w,
                                const float* __restrict__ post_w,
                                u16* __restrict__ wb, u16* __restrict__ xt) {
  const int blk = blockIdx.x;
  const int t = threadIdx.x;
  if (blk < 160) {
    const int id = blk * 256 + t;      // 40960 slots of 8 elems
    const int layer = id >> 13;        // 0..4
    const int sid = id & 8191;
    const int m = sid >> 5;
    const int s8 = sid & 31;
    const float* src = (layer < 2) ? (post_w + layer * 65536)
                                   : (pre_w + (layer - 2) * 65536);
    u16* dst = wb + layer * 65536;
    f32x4 a = *(const f32x4*)(src + m * 256 + s8 * 8);
    f32x4 c = *(const f32x4*)(src + m * 256 + s8 * 8 + 4);
    bf16x8 o;
#pragma unroll
    for (int j = 0; j < 4; j++) o[j] = (short)f2b(a[j]);
#pragma unroll
    for (int j = 0; j < 4; j++) o[4 + j] = (short)f2b(c[j]);
    *(bf16x8*)(dst + (s8 * 256 + m) * 8) = o;
  } else {
    __shared__ float tile[32 * 65];
    const int xb = blk - 160;          // 2 b x 8 ctile x 16 hwtile = 256
    const int b = xb >> 7;
    const int ct = (xb >> 4) & 7;
    const int ht = xb & 15;
    const int c0 = ct * 32, hw0 = ht * 64;
#pragma unroll
    for (int rep = 0; rep < 8; rep++) {
      const int idx = rep * 256 + t;
      const int cl = idx >> 6, hl = idx & 63;
      tile[cl * 65 + hl] = x[(b * 256 + c0 + cl) * 1024 + hw0 + hl];
    }
    __syncthreads();
    const int hl = t >> 2, c8 = t & 3;
    bf16x8 o;
#pragma unroll
    for (int i = 0; i < 8; i++) o[i] = (short)f2b(tile[(c8 * 8 + i) * 65 + hl]);
    *(bf16x8*)(xt + (b * 1024 + hw0 + hl) * 256 + c0 + c8 * 8) = o;
  }
}

// ---------------------------------------------------------------------------
// pre_gemm: 3-layer 1x1-conv chain on 2048 nodes, bf16 MFMA.
// ---------------------------------------------------------------------------
__global__ __launch_bounds__(256, 2) void dense_edge_pre(
    const u16* __restrict__ xt, const u16* __restrict__ wpre,
    const float* __restrict__ preb, u16* __restrict__ flat) {
  __shared__ u16 feat[2][4096];  // [32 s8][16 n][8] each
  const int t = threadIdx.x;
  const int wv = t >> 6, ln = t & 63;
  const int nb = blockIdx.x * 16;
  const int q4 = ln >> 4, r15 = ln & 15;

#pragma unroll
  for (int i = 0; i < 2; i++) {
    const int slot = wv * 128 + i * 64 + ln;
    const int s8 = slot >> 4, nl = slot & 15;
    gld_lds16(xt + (nb + nl) * 256 + s8 * 8, &feat[0][slot * 8]);
  }
  __syncthreads();

#pragma unroll
  for (int l = 0; l < 3; l++) {
    const u16* wl = wpre + l * 65536;
    f32x4 acc[4];
    f32x4 zero = {0.f, 0.f, 0.f, 0.f};
#pragma unroll
    for (int mt = 0; mt < 4; mt++) acc[mt] = zero;
#pragma unroll
    for (int s = 0; s < 8; s++) {
      bf16x8 bv = *(const bf16x8*)(&feat[l & 1][((s * 4 + q4) * 16 + r15) * 8]);
#pragma unroll
      for (int mt = 0; mt < 4; mt++) {
        bf16x8 av = *(const bf16x8*)(wl + ((s * 4 + q4) * 256 + wv * 64 + mt * 16 + r15) * 8);
        acc[mt] = __builtin_amdgcn_mfma_f32_16x16x32_bf16(av, bv, acc[mt], 0, 0, 0);
      }
    }
    if (l < 2) {
#pragma unroll
      for (int mt = 0; mt < 4; mt++) {
        const int o = wv * 64 + mt * 16 + q4 * 4;
        f32x4 bb = *(const f32x4*)(preb + l * 256 + o);
        u16x4 pk;
#pragma unroll
        for (int r = 0; r < 4; r++) {
          float v = fmaxf(acc[mt][r] + bb[r], 0.f);
          pk[r] = f2b(v);
        }
        *(u16x4*)(&feat[(l + 1) & 1][((o >> 3) * 16 + r15) * 8 + (o & 7)]) = pk;
      }
      __syncthreads();
    } else {
#pragma unroll
      for (int mt = 0; mt < 4; mt++) {
        const int o = wv * 64 + mt * 16 + q4 * 4;
        f32x4 bb = *(const f32x4*)(preb + 512 + o);
        u16x4 pk;
#pragma unroll
        for (int r = 0; r < 4; r++) pk[r] = f2b(acc[mt][r] + bb[r]);  // no relu
        *(u16x4*)(flat + (nb + r15) * 256 + o) = pk;
      }
    }
  }
}

// ---------------------------------------------------------------------------
// main v5: SYMMETRIC software pipeline, ONE barrier per iteration.
// 512 thr = 8 waves, each owns 32 output rows of BOTH W1 and W2
// (64+64 weight VGPRs; ~210 regs peak, fits 2 waves/EU cap -> no spill).
// Phase j (all waves identical work):
//   XX-build(j+1) | GEMM1(j)->t1[j&1] | GEMM2(j-1)+W3 epi -> pbuf[(j-1)&1]
//   | out(j-2) | gld qstage(j+2) ; barrier.
// Both GEMMs issue MFMA in EVERY phase -> 2 MFMA-active waves per SIMD cover
// each other's ds_read waits (R2's role-split serialized the GEMMs across
// barriers: only 1 MFMA wave/SIMD per phase, MfmaUtil 28.6%).
// LDS: xx 2x32K + t1 2x32K + pstage 4K + qstage 8K + pbuf 8K = 148 KB.
// ---------------------------------------------------------------------------
#define NT 8  // tiles per block
__global__ __launch_bounds__(512, 2) void dense_edge_main(
    const u16* __restrict__ flat, const int* __restrict__ pidx,
    const int* __restrict__ cidx, const u16* __restrict__ w1s,
    const u16* __restrict__ w2s, const float* __restrict__ b1,
    const float* __restrict__ b2, const float* __restrict__ w3,
    const float* __restrict__ b3, float* __restrict__ out) {
  __shared__ u16 xxbuf[2][16384];    // [tile&1][cc(32)][n(64)][8]
  __shared__ u16 t1buf[2][16384];    // same layout
  __shared__ u16 pstage[2048];       // p-rows [cc(32)][row(8)][8]
  __shared__ u16 qstage[2][2048];    // q-rows, double-buffered by tile parity
  __shared__ float pbuf[2][8][2][64];// [tile&1][wave][o3][edge]

  const int t = threadIdx.x;
  const int wv = t >> 6;
  const int ln = t & 63;
  const int q4 = ln >> 4, r15 = ln & 15;
  const int blk = blockIdx.x;
  const int tile0 = blk * NT;
  const int b = tile0 >> 10;
  const int pt = (tile0 >> 5) & 31;
  const int qt0 = tile0 & 31;
  const int p0 = pt * 8;

  // both weight slices: 32 rows each of W1 and W2 (staged layout, 256B segs)
  bf16x8 w1f[2][8], w2f[2][8];
#pragma unroll
  for (int s = 0; s < 8; s++)
#pragma unroll
    for (int mt = 0; mt < 2; mt++) {
      const int off = ((s * 4 + q4) * 256 + wv * 32 + mt * 16 + r15) * 8;
      w1f[mt][s] = *(const bf16x8*)(w1s + off);
      w2f[mt][s] = *(const bf16x8*)(w2s + off);
    }

  // initial staging: waves 0-3 -> pstage, waves 4-7 -> qstage[0]
  {
    const int slot = (wv & 3) * 64 + ln;
    const int row = slot & 7, cc = slot >> 3;
    if (wv < 4) {
      const int pn = pidx[b * 256 + p0 + row];
      gld_lds16(flat + pn * 256 + cc * 8, &pstage[slot * 8]);
    } else {
      const int qn = cidx[b * 256 + qt0 * 8 + row];
      gld_lds16(flat + qn * 256 + cc * 8, &qstage[0][slot * 8]);
    }
  }
  __syncthreads();

  const int prow = ln >> 3, qrow = ln & 7;

  // prologue phase: build XX(0); issue q-gather for tile 1
  {
    const u16* qs = qstage[0];
#pragma unroll
    for (int i = 0; i < 4; i++) {
      const int cc = wv * 4 + i;
      bf16x8 av = *(const bf16x8*)(&pstage[(cc * 8 + prow) * 8]);
      bf16x8 bv = *(const bf16x8*)(&qs[(cc * 8 + qrow) * 8]);
      bf16x8 ov;
#pragma unroll
      for (int jj = 0; jj < 8; jj++) {
        float d = b2f((u16)av[jj]) - b2f((u16)bv[jj]);
        ov[jj] = (short)f2b(d * d);
      }
      *(bf16x8*)(&xxbuf[0][(cc * 64 + ln) * 8]) = ov;
    }
    if (wv >= 4) {
      const int slot = (wv - 4) * 64 + ln;
      const int qn = cidx[b * 256 + (qt0 + 1) * 8 + (slot & 7)];
      gld_lds16(flat + qn * 256 + (slot >> 3) * 8, &qstage[1][slot * 8]);
    }
  }
  __syncthreads();

#pragma unroll 1
  for (int j = 0; j <= NT; j++) {
    // ---- XX-build(j+1) ----
    if (j < NT - 1) {
      const u16* qs = qstage[(j + 1) & 1];
#pragma unroll
      for (int i = 0; i < 4; i++) {
        const int cc = wv * 4 + i;
        bf16x8 av = *(const bf16x8*)(&pstage[(cc * 8 + prow) * 8]);
        bf16x8 bv = *(const bf16x8*)(&qs[(cc * 8 + qrow) * 8]);
        bf16x8 ov;
#pragma unroll
        for (int jj = 0; jj < 8; jj++) {
          float d = b2f((u16)av[jj]) - b2f((u16)bv[jj]);
          ov[jj] = (short)f2b(d * d);
        }
        *(bf16x8*)(&xxbuf[(j + 1) & 1][(cc * 64 + ln) * 8]) = ov;
      }
    }
    // ---- q-gather for tile j+2 (lands at this phase's barrier) ----
    if (j < NT - 2 && wv >= 4) {
      const int slot = (wv - 4) * 64 + ln;
      const int qn = cidx[b * 256 + (qt0 + j + 2) * 8 + (slot & 7)];
      gld_lds16(flat + qn * 256 + (slot >> 3) * 8,
                &qstage[(j + 2) & 1][slot * 8]);
    }
    // ---- GEMM1(j): xx -> t1 ----
    if (j < NT) {
      const u16* xb = xxbuf[j & 1];
      f32x4 acc[2][4];
      {
        f32x4 zero = {0.f, 0.f, 0.f, 0.f};
#pragma unroll
        for (int mt = 0; mt < 2; mt++)
#pragma unroll
          for (int nt = 0; nt < 4; nt++) acc[mt][nt] = zero;
      }
#pragma unroll
      for (int s = 0; s < 8; s++) {
        bf16x8 bfr[4];
#pragma unroll
        for (int nt = 0; nt < 4; nt++)
          bfr[nt] = *(const bf16x8*)(xb + ((s * 4 + q4) * 64 + nt * 16 + r15) * 8);
#pragma unroll
        for (int mt = 0; mt < 2; mt++)
#pragma unroll
          for (int nt = 0; nt < 4; nt++)
            acc[mt][nt] = __builtin_amdgcn_mfma_f32_16x16x32_bf16(w1f[mt][s], bfr[nt], acc[mt][nt], 0, 0, 0);
      }
#pragma unroll
      for (int mt = 0; mt < 2; mt++) {
        const int o = wv * 32 + mt * 16 + q4 * 4;
        f32x4 bb = *(const f32x4*)(b1 + o);
#pragma unroll
        for (int nt = 0; nt < 4; nt++) {
          const int nn = nt * 16 + r15;
          u16x4 pk;
#pragma unroll
          for (int r = 0; r < 4; r++) {
            float v = fmaxf(acc[mt][nt][r] + bb[r], 0.f);
            pk[r] = f2b(v);
          }
          *(u16x4*)(&t1buf[j & 1][((o >> 3) * 64 + nn) * 8 + (o & 7)]) = pk;
        }
      }
    }
    // ---- GEMM2(j-1): t1 -> W3 epilogue partials ----
    if (j > 0) {
      const int jm = j - 1;
      const u16* tb = t1buf[jm & 1];
      f32x4 acc[2][4];
      {
        f32x4 zero = {0.f, 0.f, 0.f, 0.f};
#pragma unroll
        for (int mt = 0; mt < 2; mt++)
#pragma unroll
          for (int nt = 0; nt < 4; nt++) acc[mt][nt] = zero;
      }
#pragma unroll
      for (int s = 0; s < 8; s++) {
        bf16x8 bfr[4];
#pragma unroll
        for (int nt = 0; nt < 4; nt++)
          bfr[nt] = *(const bf16x8*)(tb + ((s * 4 + q4) * 64 + nt * 16 + r15) * 8);
#pragma unroll
        for (int mt = 0; mt < 2; mt++)
#pragma unroll
          for (int nt = 0; nt < 4; nt++)
            acc[mt][nt] = __builtin_amdgcn_mfma_f32_16x16x32_bf16(w2f[mt][s], bfr[nt], acc[mt][nt], 0, 0, 0);
      }
      float part[2][4] = {{0.f, 0.f, 0.f, 0.f}, {0.f, 0.f, 0.f, 0.f}};
#pragma unroll
      for (int mt = 0; mt < 2; mt++) {
        const int o = wv * 32 + mt * 16 + q4 * 4;
        f32x4 bb = *(const f32x4*)(b2 + o);
        f32x4 w3a = *(const f32x4*)(w3 + o);
        f32x4 w3b = *(const f32x4*)(w3 + 256 + o);
#pragma unroll
        for (int nt = 0; nt < 4; nt++) {
#pragma unroll
          for (int r = 0; r < 4; r++) {
            float v = fmaxf(acc[mt][nt][r] + bb[r], 0.f);
            part[0][nt] += v * w3a[r];
            part[1][nt] += v * w3b[r];
          }
        }
      }
#pragma unroll
      for (int o3 = 0; o3 < 2; o3++)
#pragma unroll
        for (int nt = 0; nt < 4; nt++) {
          part[o3][nt] += __shfl_xor(part[o3][nt], 16, 64);
          part[o3][nt] += __shfl_xor(part[o3][nt], 32, 64);
        }
      if (q4 == 0) {
#pragma unroll
        for (int o3 = 0; o3 < 2; o3++)
#pragma unroll
          for (int nt = 0; nt < 4; nt++)
            pbuf[jm & 1][wv][o3][nt * 16 + r15] = part[o3][nt];
      }
    }
    // ---- out(j-2) ----
    if (j >= 2 && t < 128) {
      const int jo = j - 2;
      const int o3 = t >> 6;
      const int n = t & 63;
      float v = b3[o3];
#pragma unroll
      for (int k = 0; k < 8; k++) v += pbuf[jo & 1][k][o3][n];
      out[((b * 2 + o3) * 256 + p0 + (n >> 3)) * 256 + (qt0 + jo) * 8 + (n & 7)] = v;
    }
    __syncthreads();
  }

  // epilogue: out(NT-1)
  if (t < 128) {
    const int jo = NT - 1;
    const int o3 = t >> 6;
    const int n = t & 63;
    float v = b3[o3];
#pragma unroll
    for (int k = 0; k < 8; k++) v += pbuf[jo & 1][k][o3][n];
    out[((b * 2 + o3) * 256 + p0 + (n >> 3)) * 256 + (qt0 + jo) * 8 + (n & 7)] = v;
  }
}

// ---------------------------------------------------------------------------
extern "C" void kernel_launch(void* const* d_in, const int* in_sizes, int n_in,
                              void* d_out, int out_size, void* d_ws, size_t ws_size,
                              hipStream_t stream) {
  (void)in_sizes; (void)n_in; (void)out_size; (void)ws_size;
  const float* x          = (const float*)d_in[0];
  const int*   pidx       = (const int*)d_in[1];
  const int*   cidx       = (const int*)d_in[2];
  const float* pre_w      = (const float*)d_in[3];
  const float* pre_b      = (const float*)d_in[4];
  const float* post_w     = (const float*)d_in[5];
  const float* post_b     = (const float*)d_in[6];
  const float* post_out_w = (const float*)d_in[7];
  const float* post_out_b = (const float*)d_in[8];
  float* out = (float*)d_out;

  u16* ws   = (u16*)d_ws;
  u16* wb   = ws;              // staged bf16 weights: w1,w2,pre0,pre1,pre2
  u16* w1s  = wb;
  u16* w2s  = wb + 65536;
  u16* wpre = wb + 131072;
  u16* xt   = ws + 327680;     // x_t bf16 [2048][256]
  u16* flat = ws + 851968;     // node features bf16 [2048][256]

  dense_edge_prep<<<416, 256, 0, stream>>>(x, pre_w, post_w, wb, xt);
  dense_edge_pre<<<128, 256, 0, stream>>>(xt, wpre, pre_b, flat);
  dense_edge_main<<<256, 512, 0, stream>>>(flat, pidx, cidx, w1s, w2s,
                                           post_b, post_b + 256,
                                           post_out_w, post_out_b, out);
}

// Round 6
// 117.221 us; speedup vs baseline: 1.6929x; 1.0196x over previous
//
#include <hip/hip_runtime.h>

typedef unsigned short u16;
typedef short bf16x8 __attribute__((ext_vector_type(8)));
typedef float f32x4 __attribute__((ext_vector_type(4)));
typedef u16 u16x4 __attribute__((ext_vector_type(4)));

__device__ __forceinline__ float b2f(u16 h) {
  unsigned u = ((unsigned)h) << 16;
  return __builtin_bit_cast(float, u);
}
// native RTNE f32->bf16; compiler pairs these into v_cvt_pk_bf16_f32
__device__ __forceinline__ u16 f2b(float f) {
  return __builtin_bit_cast(u16, (__bf16)f);
}
__device__ __forceinline__ void gld_lds16(const void* g, void* l) {
  __builtin_amdgcn_global_load_lds(
      (__attribute__((address_space(1))) void*)(g),
      (__attribute__((address_space(3))) void*)(l), 16, 0, 0);
}

// ---------------------------------------------------------------------------
// prep (merged): blocks [0,160): fp32 [o][c] weights -> bf16 STAGED layout
//   [layer][s8(32)][m(256)][8]  (a wave's A-frag reads are 256B-contiguous)
//   layers: 0,1 = post_w[0..1]; 2,3,4 = pre_w[0..2]
// blocks [160,416): x [2][256][1024] fp32 -> xt [2048][256] bf16 (transpose)
// ---------------------------------------------------------------------------
__global__ void dense_edge_prep(const float* __restrict__ x,
                                const float* __restrict__ pre_w,
                                const float* __restrict__ post_w,
                                u16* __restrict__ wb, u16* __restrict__ xt) {
  const int blk = blockIdx.x;
  const int t = threadIdx.x;
  if (blk < 160) {
    const int id = blk * 256 + t;      // 40960 slots of 8 elems
    const int layer = id >> 13;        // 0..4
    const int sid = id & 8191;
    const int m = sid >> 5;
    const int s8 = sid & 31;
    const float* src = (layer < 2) ? (post_w + layer * 65536)
                                   : (pre_w + (layer - 2) * 65536);
    u16* dst = wb + layer * 65536;
    f32x4 a = *(const f32x4*)(src + m * 256 + s8 * 8);
    f32x4 c = *(const f32x4*)(src + m * 256 + s8 * 8 + 4);
    bf16x8 o;
#pragma unroll
    for (int j = 0; j < 4; j++) o[j] = (short)f2b(a[j]);
#pragma unroll
    for (int j = 0; j < 4; j++) o[4 + j] = (short)f2b(c[j]);
    *(bf16x8*)(dst + (s8 * 256 + m) * 8) = o;
  } else {
    __shared__ float tile[32 * 65];
    const int xb = blk - 160;          // 2 b x 8 ctile x 16 hwtile = 256
    const int b = xb >> 7;
    const int ct = (xb >> 4) & 7;
    const int ht = xb & 15;
    const int c0 = ct * 32, hw0 = ht * 64;
#pragma unroll
    for (int rep = 0; rep < 8; rep++) {
      const int idx = rep * 256 + t;
      const int cl = idx >> 6, hl = idx & 63;
      tile[cl * 65 + hl] = x[(b * 256 + c0 + cl) * 1024 + hw0 + hl];
    }
    __syncthreads();
    const int hl = t >> 2, c8 = t & 3;
    bf16x8 o;
#pragma unroll
    for (int i = 0; i < 8; i++) o[i] = (short)f2b(tile[(c8 * 8 + i) * 65 + hl]);
    *(bf16x8*)(xt + (b * 1024 + hw0 + hl) * 256 + c0 + c8 * 8) = o;
  }
}

// ---------------------------------------------------------------------------
// pre_gemm: 3-layer 1x1-conv chain on 2048 nodes, bf16 MFMA.
// ---------------------------------------------------------------------------
__global__ __launch_bounds__(256, 2) void dense_edge_pre(
    const u16* __restrict__ xt, const u16* __restrict__ wpre,
    const float* __restrict__ preb, u16* __restrict__ flat) {
  __shared__ u16 feat[2][4096];  // [32 s8][16 n][8] each
  const int t = threadIdx.x;
  const int wv = t >> 6, ln = t & 63;
  const int nb = blockIdx.x * 16;
  const int q4 = ln >> 4, r15 = ln & 15;

#pragma unroll
  for (int i = 0; i < 2; i++) {
    const int slot = wv * 128 + i * 64 + ln;
    const int s8 = slot >> 4, nl = slot & 15;
    gld_lds16(xt + (nb + nl) * 256 + s8 * 8, &feat[0][slot * 8]);
  }
  __syncthreads();

#pragma unroll
  for (int l = 0; l < 3; l++) {
    const u16* wl = wpre + l * 65536;
    f32x4 acc[4];
    f32x4 zero = {0.f, 0.f, 0.f, 0.f};
#pragma unroll
    for (int mt = 0; mt < 4; mt++) acc[mt] = zero;
#pragma unroll
    for (int s = 0; s < 8; s++) {
      bf16x8 bv = *(const bf16x8*)(&feat[l & 1][((s * 4 + q4) * 16 + r15) * 8]);
#pragma unroll
      for (int mt = 0; mt < 4; mt++) {
        bf16x8 av = *(const bf16x8*)(wl + ((s * 4 + q4) * 256 + wv * 64 + mt * 16 + r15) * 8);
        acc[mt] = __builtin_amdgcn_mfma_f32_16x16x32_bf16(av, bv, acc[mt], 0, 0, 0);
      }
    }
    if (l < 2) {
#pragma unroll
      for (int mt = 0; mt < 4; mt++) {
        const int o = wv * 64 + mt * 16 + q4 * 4;
        f32x4 bb = *(const f32x4*)(preb + l * 256 + o);
        u16x4 pk;
#pragma unroll
        for (int r = 0; r < 4; r++) {
          float v = fmaxf(acc[mt][r] + bb[r], 0.f);
          pk[r] = f2b(v);
        }
        *(u16x4*)(&feat[(l + 1) & 1][((o >> 3) * 16 + r15) * 8 + (o & 7)]) = pk;
      }
      __syncthreads();
    } else {
#pragma unroll
      for (int mt = 0; mt < 4; mt++) {
        const int o = wv * 64 + mt * 16 + q4 * 4;
        f32x4 bb = *(const f32x4*)(preb + 512 + o);
        u16x4 pk;
#pragma unroll
        for (int r = 0; r < 4; r++) pk[r] = f2b(acc[mt][r] + bb[r]);  // no relu
        *(u16x4*)(flat + (nb + r15) * 256 + o) = pk;
      }
    }
  }
}

// ---------------------------------------------------------------------------
// main v6: symmetric pipeline + WAVE-PARITY STAGGER.
// v5's MfmaUtil==VALUBusy==26% showed the 2 waves/SIMD run in lockstep:
// both in XX (MFMA idle) or both in GEMM (VALU idle). Even waves run
// [G1,G2,XX], odd waves [XX,G2,G1] -> one wave's MFMA covers the other's
// VALU/LDS. Also: cidx preloaded to rotating reg (no per-phase L2 wait),
// q-gld issued at phase TOP, out-store at phase TOP (drains under compute),
// p-rows hoisted to regs, s_setprio(1) around MFMA loops.
// ---------------------------------------------------------------------------
#define NT 8  // tiles per block
__global__ __launch_bounds__(512, 2) void dense_edge_main(
    const u16* __restrict__ flat, const int* __restrict__ pidx,
    const int* __restrict__ cidx, const u16* __restrict__ w1s,
    const u16* __restrict__ w2s, const float* __restrict__ b1,
    const float* __restrict__ b2, const float* __restrict__ w3,
    const float* __restrict__ b3, float* __restrict__ out) {
  __shared__ u16 xxbuf[2][16384];    // [tile&1][cc(32)][n(64)][8]
  __shared__ u16 t1buf[2][16384];    // same layout
  __shared__ u16 pstage[2048];       // p-rows [cc(32)][row(8)][8]
  __shared__ u16 qstage[2][2048];    // q-rows, double-buffered by tile parity
  __shared__ float pbuf[2][8][2][64];// [tile&1][wave][o3][edge]

  const int t = threadIdx.x;
  const int wv = t >> 6;
  const int ln = t & 63;
  const int q4 = ln >> 4, r15 = ln & 15;
  const int blk = blockIdx.x;
  const int tile0 = blk * NT;
  const int b = tile0 >> 10;
  const int pt = (tile0 >> 5) & 31;
  const int qt0 = tile0 & 31;
  const int p0 = pt * 8;

  // both weight slices: 32 rows each of W1 and W2 (staged layout, 256B segs)
  bf16x8 w1f[2][8], w2f[2][8];
#pragma unroll
  for (int s = 0; s < 8; s++)
#pragma unroll
    for (int mt = 0; mt < 2; mt++) {
      const int off = ((s * 4 + q4) * 256 + wv * 32 + mt * 16 + r15) * 8;
      w1f[mt][s] = *(const bf16x8*)(w1s + off);
      w2f[mt][s] = *(const bf16x8*)(w2s + off);
    }

  // initial staging: waves 0-3 -> pstage, waves 4-7 -> qstage[0]
  const int slot4 = (wv & 3) * 64 + ln;
  const int srow = slot4 & 7, scc = slot4 >> 3;
  if (wv < 4) {
    const int pn = pidx[b * 256 + p0 + srow];
    gld_lds16(flat + pn * 256 + scc * 8, &pstage[slot4 * 8]);
  } else {
    const int qn = cidx[b * 256 + qt0 * 8 + srow];
    gld_lds16(flat + qn * 256 + scc * 8, &qstage[0][slot4 * 8]);
  }
  // preload q indices: tile 1 (prologue gld) and tile 2 (phase-0 gld)
  int qn_pro = 0, qn_cur = 0;
  if (wv >= 4) {
    qn_pro = cidx[b * 256 + (qt0 + 1) * 8 + srow];
    qn_cur = cidx[b * 256 + (qt0 + 2) * 8 + srow];
  }
  __syncthreads();

  const int prow = ln >> 3, qrow = ln & 7;

  // p-rows constant across tiles: hoist to registers (frees LDS path in XX)
  bf16x8 pa[4];
#pragma unroll
  for (int i = 0; i < 4; i++)
    pa[i] = *(const bf16x8*)(&pstage[((wv * 4 + i) * 8 + prow) * 8]);

  // ---- work items as lambdas (inlined twice for parity stagger) ----
  auto do_xx = [&](int jx) {
    const u16* qs = qstage[jx & 1];
    u16* xb = xxbuf[jx & 1];
#pragma unroll
    for (int i = 0; i < 4; i++) {
      const int cc = wv * 4 + i;
      bf16x8 av = pa[i];
      bf16x8 bv = *(const bf16x8*)(&qs[(cc * 8 + qrow) * 8]);
      bf16x8 ov;
#pragma unroll
      for (int jj = 0; jj < 8; jj++) {
        float d = b2f((u16)av[jj]) - b2f((u16)bv[jj]);
        ov[jj] = (short)f2b(d * d);
      }
      *(bf16x8*)(&xb[(cc * 64 + ln) * 8]) = ov;
    }
  };

  auto do_g1 = [&](int jg) {
    const u16* xb = xxbuf[jg & 1];
    f32x4 acc[2][4];
    {
      f32x4 zero = {0.f, 0.f, 0.f, 0.f};
#pragma unroll
      for (int mt = 0; mt < 2; mt++)
#pragma unroll
        for (int nt = 0; nt < 4; nt++) acc[mt][nt] = zero;
    }
    __builtin_amdgcn_s_setprio(1);
#pragma unroll
    for (int s = 0; s < 8; s++) {
      bf16x8 bfr[4];
#pragma unroll
      for (int nt = 0; nt < 4; nt++)
        bfr[nt] = *(const bf16x8*)(xb + ((s * 4 + q4) * 64 + nt * 16 + r15) * 8);
#pragma unroll
      for (int mt = 0; mt < 2; mt++)
#pragma unroll
        for (int nt = 0; nt < 4; nt++)
          acc[mt][nt] = __builtin_amdgcn_mfma_f32_16x16x32_bf16(w1f[mt][s], bfr[nt], acc[mt][nt], 0, 0, 0);
    }
    __builtin_amdgcn_s_setprio(0);
#pragma unroll
    for (int mt = 0; mt < 2; mt++) {
      const int o = wv * 32 + mt * 16 + q4 * 4;
      f32x4 bb = *(const f32x4*)(b1 + o);
#pragma unroll
      for (int nt = 0; nt < 4; nt++) {
        const int nn = nt * 16 + r15;
        u16x4 pk;
#pragma unroll
        for (int r = 0; r < 4; r++) {
          float v = fmaxf(acc[mt][nt][r] + bb[r], 0.f);
          pk[r] = f2b(v);
        }
        *(u16x4*)(&t1buf[jg & 1][((o >> 3) * 64 + nn) * 8 + (o & 7)]) = pk;
      }
    }
  };

  auto do_g2 = [&](int jg) {
    const u16* tb = t1buf[jg & 1];
    f32x4 acc[2][4];
    {
      f32x4 zero = {0.f, 0.f, 0.f, 0.f};
#pragma unroll
      for (int mt = 0; mt < 2; mt++)
#pragma unroll
        for (int nt = 0; nt < 4; nt++) acc[mt][nt] = zero;
    }
    __builtin_amdgcn_s_setprio(1);
#pragma unroll
    for (int s = 0; s < 8; s++) {
      bf16x8 bfr[4];
#pragma unroll
      for (int nt = 0; nt < 4; nt++)
        bfr[nt] = *(const bf16x8*)(tb + ((s * 4 + q4) * 64 + nt * 16 + r15) * 8);
#pragma unroll
      for (int mt = 0; mt < 2; mt++)
#pragma unroll
        for (int nt = 0; nt < 4; nt++)
          acc[mt][nt] = __builtin_amdgcn_mfma_f32_16x16x32_bf16(w2f[mt][s], bfr[nt], acc[mt][nt], 0, 0, 0);
    }
    __builtin_amdgcn_s_setprio(0);
    float part[2][4] = {{0.f, 0.f, 0.f, 0.f}, {0.f, 0.f, 0.f, 0.f}};
#pragma unroll
    for (int mt = 0; mt < 2; mt++) {
      const int o = wv * 32 + mt * 16 + q4 * 4;
      f32x4 bb = *(const f32x4*)(b2 + o);
      f32x4 w3a = *(const f32x4*)(w3 + o);
      f32x4 w3b = *(const f32x4*)(w3 + 256 + o);
#pragma unroll
      for (int nt = 0; nt < 4; nt++) {
#pragma unroll
        for (int r = 0; r < 4; r++) {
          float v = fmaxf(acc[mt][nt][r] + bb[r], 0.f);
          part[0][nt] += v * w3a[r];
          part[1][nt] += v * w3b[r];
        }
      }
    }
#pragma unroll
    for (int o3 = 0; o3 < 2; o3++)
#pragma unroll
      for (int nt = 0; nt < 4; nt++) {
        part[o3][nt] += __shfl_xor(part[o3][nt], 16, 64);
        part[o3][nt] += __shfl_xor(part[o3][nt], 32, 64);
      }
    if (q4 == 0) {
#pragma unroll
      for (int o3 = 0; o3 < 2; o3++)
#pragma unroll
        for (int nt = 0; nt < 4; nt++)
          pbuf[jg & 1][wv][o3][nt * 16 + r15] = part[o3][nt];
    }
  };

  // prologue: XX(0); issue q-gather for tile 1
  do_xx(0);
  if (wv >= 4) gld_lds16(flat + qn_pro * 256 + scc * 8, &qstage[1][slot4 * 8]);
  __syncthreads();

#pragma unroll 1
  for (int j = 0; j <= NT; j++) {
    // ---- early: out(j-2) global store (drains under this phase's compute)
    if (j >= 2 && t < 128) {
      const int jo = j - 2;
      const int o3 = t >> 6;
      const int n = t & 63;
      float v = b3[o3];
#pragma unroll
      for (int k = 0; k < 8; k++) v += pbuf[jo & 1][k][o3][n];
      out[((b * 2 + o3) * 256 + p0 + (n >> 3)) * 256 + (qt0 + jo) * 8 + (n & 7)] = v;
    }
    // ---- early: q-gather for tile j+2 (address already in reg)
    if (j < NT - 2 && wv >= 4) {
      gld_lds16(flat + qn_cur * 256 + scc * 8, &qstage[j & 1][slot4 * 8]);
      if (j < NT - 3) qn_cur = cidx[b * 256 + (qt0 + j + 3) * 8 + srow];
    }
    // ---- parity-staggered work ----
    if (wv & 1) {
      if (j < NT - 1) do_xx(j + 1);
      if (j > 0) do_g2(j - 1);
      if (j < NT) do_g1(j);
    } else {
      if (j < NT) do_g1(j);
      if (j > 0) do_g2(j - 1);
      if (j < NT - 1) do_xx(j + 1);
    }
    __syncthreads();
  }

  // epilogue: out(NT-1)
  if (t < 128) {
    const int jo = NT - 1;
    const int o3 = t >> 6;
    const int n = t & 63;
    float v = b3[o3];
#pragma unroll
    for (int k = 0; k < 8; k++) v += pbuf[jo & 1][k][o3][n];
    out[((b * 2 + o3) * 256 + p0 + (n >> 3)) * 256 + (qt0 + jo) * 8 + (n & 7)] = v;
  }
}

// ---------------------------------------------------------------------------
extern "C" void kernel_launch(void* const* d_in, const int* in_sizes, int n_in,
                              void* d_out, int out_size, void* d_ws, size_t ws_size,
                              hipStream_t stream) {
  (void)in_sizes; (void)n_in; (void)out_size; (void)ws_size;
  const float* x          = (const float*)d_in[0];
  const int*   pidx       = (const int*)d_in[1];
  const int*   cidx       = (const int*)d_in[2];
  const float* pre_w      = (const float*)d_in[3];
  const float* pre_b      = (const float*)d_in[4];
  const float* post_w     = (const float*)d_in[5];
  const float* post_b     = (const float*)d_in[6];
  const float* post_out_w = (const float*)d_in[7];
  const float* post_out_b = (const float*)d_in[8];
  float* out = (float*)d_out;

  u16* ws   = (u16*)d_ws;
  u16* wb   = ws;              // staged bf16 weights: w1,w2,pre0,pre1,pre2
  u16* w1s  = wb;
  u16* w2s  = wb + 65536;
  u16* wpre = wb + 131072;
  u16* xt   = ws + 327680;     // x_t bf16 [2048][256]
  u16* flat = ws + 851968;     // node features bf16 [2048][256]

  dense_edge_prep<<<416, 256, 0, stream>>>(x, pre_w, post_w, wb, xt);
  dense_edge_pre<<<128, 256, 0, stream>>>(xt, wpre, pre_b, flat);
  dense_edge_main<<<256, 512, 0, stream>>>(flat, pidx, cidx, w1s, w2s,
                                           post_b, post_b + 256,
                                           post_out_w, post_out_b, out);
}